// Round 1
// baseline (406.050 us; speedup 1.0000x reference)
//
#include <hip/hip_runtime.h>
#include <hip/hip_bf16.h>
#include <stdint.h>

// Problem constants (match reference)
#define kN   20000
#define kE   160000
#define kET  (kN + kE)   // edges incl self loops = 180000
#define kF   256
#define kHID 64
#define kH   4
#define kHC  16
#define kC   10
#define kK   3
#define kCST 1e-5f

__device__ __forceinline__ uint16_t f2bf(float x) {
    uint32_t u = __float_as_uint(x);
    u += 0x7fffu + ((u >> 16) & 1u);   // round-to-nearest-even
    return (uint16_t)(u >> 16);
}
__device__ __forceinline__ float bf2f(uint16_t h) {
    return __uint_as_float(((uint32_t)h) << 16);
}

// ---- degree histogram over col (incl self loops) ----
__global__ void deg_kernel(const int* __restrict__ ei, int* __restrict__ deg) {
    int e = blockIdx.x * blockDim.x + threadIdx.x;
    if (e >= kET) return;
    int c = (e < kE) ? ei[kE + e] : (e - kE);
    atomicAdd(&deg[c], 1);
}

// ---- dis = 1/sqrt(deg) (deg >= 1 always due to self loops) ----
__global__ void dis_kernel(const int* __restrict__ deg, float* __restrict__ dis) {
    int n = blockIdx.x * blockDim.x + threadIdx.x;
    if (n >= kN) return;
    dis[n] = 1.0f / sqrtf((float)deg[n]);
}

// ---- single-block exclusive scan of deg -> ptr[0..N] ----
__global__ void scan_kernel(const int* __restrict__ deg, int* __restrict__ ptr) {
    __shared__ int sd[1024];
    __shared__ int carry;
    int t = threadIdx.x;
    if (t == 0) { carry = 0; ptr[0] = 0; }
    __syncthreads();
    for (int base = 0; base < kN; base += 1024) {
        int i = base + t;
        int v = (i < kN) ? deg[i] : 0;
        sd[t] = v;
        __syncthreads();
        for (int off = 1; off < 1024; off <<= 1) {
            int add = (t >= off) ? sd[t - off] : 0;
            __syncthreads();
            sd[t] += add;
            __syncthreads();
        }
        int total = sd[1023];
        if (i < kN) ptr[i + 1] = carry + sd[t];
        __syncthreads();
        if (t == 0) carry += total;
        // next-iter top barrier orders the carry update before reads
    }
}

// ---- CSR (by col) build: scatter (row, norm) ----
__global__ void scatter_kernel(const int* __restrict__ ei, const float* __restrict__ dis,
                               const int* __restrict__ ptr, int* __restrict__ cursor,
                               int* __restrict__ src, float* __restrict__ wgt) {
    int e = blockIdx.x * blockDim.x + threadIdx.x;
    if (e >= kET) return;
    int r, c;
    if (e < kE) { r = ei[e]; c = ei[kE + e]; } else { r = c = e - kE; }
    float wv = dis[r] * dis[c];
    int pos = ptr[c] + atomicAdd(&cursor[c], 1);
    src[pos] = r;
    wgt[pos] = wv;
}

// ---- gamma precompute: gammas[hop][h] = hopwise[hop+1]*softmax_over_heads(temp)[h,hop+1]
__global__ void gamma_kernel(const float* __restrict__ hopwise, const float* __restrict__ temp,
                             float* __restrict__ gammas) {
    if (threadIdx.x == 0 && blockIdx.x == 0) {
        for (int k = 1; k <= kK; ++k) {
            float mx = -1e30f;
            for (int h = 0; h < kH; ++h) mx = fmaxf(mx, temp[h * (kK + 1) + k]);
            float ex[kH]; float s = 0.f;
            for (int h = 0; h < kH; ++h) { ex[h] = __expf(temp[h * (kK + 1) + k] - mx); s += ex[h]; }
            for (int h = 0; h < kH; ++h) gammas[(k - 1) * kH + h] = hopwise[k] * ex[h] / s;
        }
    }
}

// ---- fused: x = relu(feat@W_in+b), Q/K = 1+elu(x@W+b), V = x@Wv+b,
//             M0 = K outer V (bf16), hidden = V*hopwise[0], write Q,K f32
__global__ __launch_bounds__(256) void fused_qkv_kernel(
    const float* __restrict__ feat, const float* __restrict__ W_in, const float* __restrict__ b_in,
    const float* __restrict__ Wq, const float* __restrict__ bq,
    const float* __restrict__ Wk, const float* __restrict__ bk,
    const float* __restrict__ Wv, const float* __restrict__ bv,
    const float* __restrict__ hopwise,
    float* __restrict__ Q, float* __restrict__ Kt, float* __restrict__ hidden,
    uint16_t* __restrict__ M) {
    __shared__ float lf[4][kF];
    __shared__ float lx[4][kHID];
    __shared__ float lv[4][kH * kC];
    int w = threadIdx.x >> 6;     // node slot within block
    int t = threadIdx.x & 63;     // lane within node
    int n = blockIdx.x * 4 + w;   // grid sized exactly: 5000*4 = 20000

    // stage feature row (256 f32) : 64 threads x float4
    *(float4*)&lf[w][t * 4] = *(const float4*)(feat + (size_t)n * kF + t * 4);
    __syncthreads();

    float acc = b_in[t];
#pragma unroll 8
    for (int f = 0; f < kF; ++f) acc += lf[w][f] * W_in[f * kHID + t];
    acc = fmaxf(acc, 0.0f);
    lx[w][t] = acc;
    __syncthreads();

    float q = bq[t], k = bk[t];
#pragma unroll 8
    for (int f = 0; f < kHID; ++f) {
        float xv = lx[w][f];
        q += xv * Wq[f * kHID + t];
        k += xv * Wk[f * kHID + t];
    }
    q = (q > 0.f) ? (1.f + q) : __expf(q);   // 1 + elu
    k = (k > 0.f) ? (1.f + k) : __expf(k);
    Q[(size_t)n * kHID + t] = q;
    Kt[(size_t)n * kHID + t] = k;

    if (t < kH * kC) {
        float v = bv[t];
#pragma unroll 8
        for (int f = 0; f < kHID; ++f) v += lx[w][f] * Wv[f * (kH * kC) + t];
        lv[w][t] = v;
    }
    __syncthreads();

    float hw0 = hopwise[0];
    if (t < kH * kC) hidden[(size_t)n * (kH * kC) + t] = lv[w][t] * hw0;

    // M[n, h, i, c] = K[n,h,i] * V[n,h,c]; thread t=(h*16+i) writes 10 bf16
    int h = t >> 4;
    uint32_t* dst = (uint32_t*)(M + (size_t)n * 640 + t * 10);
#pragma unroll
    for (int c = 0; c < kC; c += 2) {
        float a = k * lv[w][h * kC + c];
        float b = k * lv[w][h * kC + c + 1];
        dst[c >> 1] = ((uint32_t)f2bf(b) << 16) | (uint32_t)f2bf(a);
    }
}

// ---- one hop: gather-propagate M (bf16) & Kt (f32), then combine into hidden
__global__ __launch_bounds__(320) void hop_kernel(
    const int* __restrict__ ptr, const int* __restrict__ src, const float* __restrict__ wgt,
    const uint16_t* __restrict__ Min, uint16_t* __restrict__ Mout,
    const float* __restrict__ Ktin, float* __restrict__ Ktout,
    const float* __restrict__ Q, float* __restrict__ hidden,
    const float* __restrict__ gammas) {
    __shared__ float Ml[640];
    __shared__ float Ktl[64];
    __shared__ float Ql[64];
    __shared__ float Cdl[4];
    int n = blockIdx.x;
    int t = threadIdx.x;
    int beg = ptr[n], end = ptr[n + 1];

    float m0 = 0.f, m1 = 0.f;
    float k0 = 0.f, k1 = 0.f;
    for (int e = beg; e < end; ++e) {
        int s = src[e];
        float wv = wgt[e];
        uint32_t p = *(const uint32_t*)(Min + (size_t)s * 640 + 2 * t);
        m0 += wv * bf2f((uint16_t)p);
        m1 += wv * bf2f((uint16_t)(p >> 16));
        if (t < 32) {
            float2 kv = *(const float2*)(Ktin + (size_t)s * 64 + 2 * t);
            k0 += wv * kv.x;
            k1 += wv * kv.y;
        }
    }
    // outputs + LDS staging
    *(uint32_t*)(Mout + (size_t)n * 640 + 2 * t) =
        ((uint32_t)f2bf(m1) << 16) | (uint32_t)f2bf(m0);
    Ml[2 * t] = m0; Ml[2 * t + 1] = m1;
    if (t < 32) {
        Ktl[2 * t] = k0; Ktl[2 * t + 1] = k1;
        *(float2*)(Ktout + (size_t)n * 64 + 2 * t) = make_float2(k0, k1);
    } else if (t < 64) {
        int i = t - 32;
        float2 qv = *(const float2*)(Q + (size_t)n * 64 + 2 * i);
        Ql[2 * i] = qv.x; Ql[2 * i + 1] = qv.y;
    }
    __syncthreads();
    if (t < kH) {
        float cd = kCST;
#pragma unroll
        for (int i = 0; i < kHC; ++i) cd += Ql[t * kHC + i] * Ktl[t * kHC + i];
        Cdl[t] = cd;
    }
    __syncthreads();
    if (t < kH * kC) {
        int h = t / kC, j = t - h * kC;
        float hh = 0.f;
#pragma unroll
        for (int i = 0; i < kHC; ++i) hh += Ql[h * kHC + i] * Ml[h * 160 + i * 10 + j];
        hidden[(size_t)n * (kH * kC) + t] += gammas[h] * hh / Cdl[h];
    }
}

// ---- out = hidden @ W_out + b_out ----
__global__ void out_kernel(const float* __restrict__ hidden, const float* __restrict__ W_out,
                           const float* __restrict__ b_out, float* __restrict__ out) {
    int idx = blockIdx.x * blockDim.x + threadIdx.x;
    if (idx >= kN * kC) return;
    int n = idx / kC, c = idx - n * kC;
    float acc = b_out[c];
    const float* hr = hidden + (size_t)n * (kH * kC);
#pragma unroll 8
    for (int i = 0; i < kH * kC; ++i) acc += hr[i] * W_out[i * kC + c];
    out[idx] = acc;
}

extern "C" void kernel_launch(void* const* d_in, const int* in_sizes, int n_in,
                              void* d_out, int out_size, void* d_ws, size_t ws_size,
                              hipStream_t stream) {
    const float* feat   = (const float*)d_in[0];
    const int*   ei     = (const int*)d_in[1];
    const float* W_in   = (const float*)d_in[2];
    const float* b_in   = (const float*)d_in[3];
    const float* Wq     = (const float*)d_in[4];
    const float* bq     = (const float*)d_in[5];
    const float* Wk     = (const float*)d_in[6];
    const float* bk     = (const float*)d_in[7];
    const float* Wv     = (const float*)d_in[8];
    const float* bv     = (const float*)d_in[9];
    const float* W_out  = (const float*)d_in[10];
    const float* b_out  = (const float*)d_in[11];
    const float* hopwise= (const float*)d_in[12];
    const float* temp   = (const float*)d_in[13];
    float* out = (float*)d_out;

    char* ws = (char*)d_ws;
    size_t off = 0;
    auto alloc = [&](size_t bytes) -> void* {
        void* p = ws + off;
        off += (bytes + 255) & ~(size_t)255;
        return p;
    };
    int*      deg    = (int*)alloc((size_t)kN * 4);
    int*      cursor = (int*)alloc((size_t)kN * 4);
    int*      ptr    = (int*)alloc((size_t)(kN + 1) * 4);
    float*    dis    = (float*)alloc((size_t)kN * 4);
    int*      csrc   = (int*)alloc((size_t)kET * 4);
    float*    cwgt   = (float*)alloc((size_t)kET * 4);
    float*    Q      = (float*)alloc((size_t)kN * kHID * 4);
    float*    Kt0    = (float*)alloc((size_t)kN * kHID * 4);
    float*    Kt1    = (float*)alloc((size_t)kN * kHID * 4);
    float*    hidden = (float*)alloc((size_t)kN * kH * kC * 4);
    float*    gammas = (float*)alloc(64);
    uint16_t* M0     = (uint16_t*)alloc((size_t)kN * 640 * 2);
    uint16_t* M1     = (uint16_t*)alloc((size_t)kN * 640 * 2);
    (void)ws_size; (void)in_sizes; (void)n_in; (void)out_size;

    hipMemsetAsync(deg, 0, (size_t)kN * 4, stream);
    hipMemsetAsync(cursor, 0, (size_t)kN * 4, stream);

    deg_kernel<<<(kET + 255) / 256, 256, 0, stream>>>(ei, deg);
    dis_kernel<<<(kN + 255) / 256, 256, 0, stream>>>(deg, dis);
    scan_kernel<<<1, 1024, 0, stream>>>(deg, ptr);
    scatter_kernel<<<(kET + 255) / 256, 256, 0, stream>>>(ei, dis, ptr, cursor, csrc, cwgt);
    gamma_kernel<<<1, 64, 0, stream>>>(hopwise, temp, gammas);
    fused_qkv_kernel<<<kN / 4, 256, 0, stream>>>(feat, W_in, b_in, Wq, bq, Wk, bk, Wv, bv,
                                                 hopwise, Q, Kt0, hidden, M0);
    // hop 0: M0->M1, Kt0->Kt1 ; hop 1: M1->M0 ; hop 2: M0->M1
    hop_kernel<<<kN, 320, 0, stream>>>(ptr, csrc, cwgt, M0, M1, Kt0, Kt1, Q, hidden, gammas + 0);
    hop_kernel<<<kN, 320, 0, stream>>>(ptr, csrc, cwgt, M1, M0, Kt1, Kt0, Q, hidden, gammas + 4);
    hop_kernel<<<kN, 320, 0, stream>>>(ptr, csrc, cwgt, M0, M1, Kt0, Kt1, Q, hidden, gammas + 8);
    out_kernel<<<(kN * kC + 255) / 256, 256, 0, stream>>>(hidden, W_out, b_out, out);
}

// Round 2
// 256.969 us; speedup vs baseline: 1.5802x; 1.5802x over previous
//
#include <hip/hip_runtime.h>
#include <stdint.h>

// Problem constants (match reference)
#define kN   20000
#define kE   160000
#define kET  (kN + kE)   // edges incl self loops = 180000
#define kF   256
#define kHID 64
#define kH   4
#define kHC  16
#define kC   10
#define kK   3
#define kCST 1e-5f

__device__ __forceinline__ uint16_t f2bf(float x) {
    uint32_t u = __float_as_uint(x);
    u += 0x7fffu + ((u >> 16) & 1u);   // round-to-nearest-even
    return (uint16_t)(u >> 16);
}
__device__ __forceinline__ float lo16(uint32_t p) { return __uint_as_float(p << 16); }
__device__ __forceinline__ float hi16(uint32_t p) { return __uint_as_float(p & 0xffff0000u); }
__device__ __forceinline__ uint32_t pack2(float a, float b) {
    return ((uint32_t)f2bf(b) << 16) | (uint32_t)f2bf(a);
}

// ---- degree histogram over col (incl self loops) ----
__global__ void deg_kernel(const int* __restrict__ ei, int* __restrict__ deg) {
    int e = blockIdx.x * blockDim.x + threadIdx.x;
    if (e >= kET) return;
    int c = (e < kE) ? ei[kE + e] : (e - kE);
    atomicAdd(&deg[c], 1);
}

// ---- single-block scan: deg -> ptr[0..N]; also computes gammas ----
__global__ __launch_bounds__(1024) void scan_kernel(
    const int* __restrict__ deg, int* __restrict__ ptr,
    const float* __restrict__ hopwise, const float* __restrict__ temp,
    float* __restrict__ gammas) {
    __shared__ int wsums[16];
    __shared__ int wexcl[16];
    const int CH = 20;               // 1024*20 = 20480 >= kN
    int t = threadIdx.x;
    int base = t * CH;
    int s = 0;
    for (int i = 0; i < CH; ++i) {
        int idx = base + i;
        if (idx < kN) s += deg[idx];
    }
    int incl = s;
#pragma unroll
    for (int off = 1; off < 64; off <<= 1) {
        int v = __shfl_up(incl, off, 64);
        if ((t & 63) >= off) incl += v;
    }
    int wid = t >> 6;
    if ((t & 63) == 63) wsums[wid] = incl;
    __syncthreads();
    if (t < 16) {
        int p = 0;
        for (int j = 0; j < t; ++j) p += wsums[j];
        wexcl[t] = p;
    }
    __syncthreads();
    int running = wexcl[wid] + incl - s;   // exclusive prefix at `base`
    for (int i = 0; i < CH; ++i) {
        int idx = base + i;
        if (idx < kN) { ptr[idx] = running; running += deg[idx]; }
    }
    if (base < kN && base + CH >= kN) ptr[kN] = running;
    if (t == 0) {
        for (int k = 1; k <= kK; ++k) {
            float mx = -1e30f;
            for (int h = 0; h < kH; ++h) mx = fmaxf(mx, temp[h * (kK + 1) + k]);
            float ex[kH]; float sum = 0.f;
            for (int h = 0; h < kH; ++h) { ex[h] = __expf(temp[h * (kK + 1) + k] - mx); sum += ex[h]; }
            for (int h = 0; h < kH; ++h) gammas[(k - 1) * kH + h] = hopwise[k] * ex[h] / sum;
        }
    }
}

// ---- CSR (by col) build: scatter (row, norm); norm from deg via rsqrt ----
__global__ void scatter_kernel(const int* __restrict__ ei, const int* __restrict__ deg,
                               const int* __restrict__ ptr, int* __restrict__ cursor,
                               int* __restrict__ src, float* __restrict__ wgt) {
    int e = blockIdx.x * blockDim.x + threadIdx.x;
    if (e >= kET) return;
    int r, c;
    if (e < kE) { r = ei[e]; c = ei[kE + e]; } else { r = c = e - kE; }
    float wv = rsqrtf((float)deg[r]) * rsqrtf((float)deg[c]);
    int pos = ptr[c] + atomicAdd(&cursor[c], 1);
    src[pos] = r;
    wgt[pos] = wv;
}

// ---- fused: x = relu(feat@W_in+b), Q/K = 1+elu(x@W+b), V = x@Wv+b,
//             M0 = K outer V (bf16), hidden = V*hopwise[0], write Q,K f32
__global__ __launch_bounds__(256) void fused_qkv_kernel(
    const float* __restrict__ feat, const float* __restrict__ W_in, const float* __restrict__ b_in,
    const float* __restrict__ Wq, const float* __restrict__ bq,
    const float* __restrict__ Wk, const float* __restrict__ bk,
    const float* __restrict__ Wv, const float* __restrict__ bv,
    const float* __restrict__ hopwise,
    float* __restrict__ Q, float* __restrict__ Kt, float* __restrict__ hidden,
    uint16_t* __restrict__ M) {
    __shared__ float lf[4][kF];
    __shared__ float lx[4][kHID];
    __shared__ float lv[4][kH * kC];
    int w = threadIdx.x >> 6;     // node slot within block
    int t = threadIdx.x & 63;     // lane within node
    int n = blockIdx.x * 4 + w;   // grid sized exactly: 5000*4 = 20000

    *(float4*)&lf[w][t * 4] = *(const float4*)(feat + (size_t)n * kF + t * 4);
    __syncthreads();

    float acc = b_in[t];
#pragma unroll 8
    for (int f = 0; f < kF; ++f) acc += lf[w][f] * W_in[f * kHID + t];
    acc = fmaxf(acc, 0.0f);
    lx[w][t] = acc;
    __syncthreads();

    float q = bq[t], k = bk[t];
#pragma unroll 8
    for (int f = 0; f < kHID; ++f) {
        float xv = lx[w][f];
        q += xv * Wq[f * kHID + t];
        k += xv * Wk[f * kHID + t];
    }
    q = (q > 0.f) ? (1.f + q) : __expf(q);   // 1 + elu
    k = (k > 0.f) ? (1.f + k) : __expf(k);
    Q[(size_t)n * kHID + t] = q;
    Kt[(size_t)n * kHID + t] = k;

    if (t < kH * kC) {
        float v = bv[t];
#pragma unroll 8
        for (int f = 0; f < kHID; ++f) v += lx[w][f] * Wv[f * (kH * kC) + t];
        lv[w][t] = v;
    }
    __syncthreads();

    float hw0 = hopwise[0];
    if (t < kH * kC) hidden[(size_t)n * (kH * kC) + t] = lv[w][t] * hw0;

    int h = t >> 4;
    uint32_t* dst = (uint32_t*)(M + (size_t)n * 640 + t * 10);
#pragma unroll
    for (int c = 0; c < kC; c += 2) {
        float a = k * lv[w][h * kC + c];
        float b = k * lv[w][h * kC + c + 1];
        dst[c >> 1] = pack2(a, b);
    }
}

// ---- one hop, wave-per-node: gather M (bf16, 5 words/lane) & Kt (1 f32/lane),
//      unrolled x2 edges for MLP; epilogue computes Hh/Cd update.
//      LAST: skip M/Kt writeback, fuse output GEMM.
template<bool LAST>
__global__ __launch_bounds__(256) void hop2_kernel(
    const int* __restrict__ ptr, const int* __restrict__ src, const float* __restrict__ wgt,
    const uint16_t* __restrict__ Min, uint16_t* __restrict__ Mout,
    const float* __restrict__ Ktin, float* __restrict__ Ktout,
    const float* __restrict__ Q, float* __restrict__ hidden,
    const float* __restrict__ gammas,
    const float* __restrict__ W_out, const float* __restrict__ b_out,
    float* __restrict__ out) {
    __shared__ float Ml[4][640];
    __shared__ float Ktl[4][64];
    __shared__ float Ql[4][64];
    __shared__ float Hl[4][40];
    int w = threadIdx.x >> 6;     // node slot
    int l = threadIdx.x & 63;     // lane
    int n = blockIdx.x * 4 + w;
    int beg = ptr[n], end = ptr[n + 1];
    const uint32_t* Mw = (const uint32_t*)Min;

    float m0=0,m1=0,m2=0,m3=0,m4=0,m5=0,m6=0,m7=0,m8=0,m9=0;
    float kacc = 0.f;
    int e = beg;
    for (; e + 2 <= end; e += 2) {
        int s0 = src[e], s1 = src[e + 1];
        float w0 = wgt[e], w1 = wgt[e + 1];
        const uint32_t* r0 = Mw + (size_t)s0 * 320 + l;
        const uint32_t* r1 = Mw + (size_t)s1 * 320 + l;
        uint32_t a0 = r0[0], a1 = r0[64], a2 = r0[128], a3 = r0[192], a4 = r0[256];
        uint32_t b0 = r1[0], b1 = r1[64], b2 = r1[128], b3 = r1[192], b4 = r1[256];
        float ka = Ktin[(size_t)s0 * 64 + l], kb = Ktin[(size_t)s1 * 64 + l];
        m0 += w0 * lo16(a0); m1 += w0 * hi16(a0);
        m2 += w0 * lo16(a1); m3 += w0 * hi16(a1);
        m4 += w0 * lo16(a2); m5 += w0 * hi16(a2);
        m6 += w0 * lo16(a3); m7 += w0 * hi16(a3);
        m8 += w0 * lo16(a4); m9 += w0 * hi16(a4);
        m0 += w1 * lo16(b0); m1 += w1 * hi16(b0);
        m2 += w1 * lo16(b1); m3 += w1 * hi16(b1);
        m4 += w1 * lo16(b2); m5 += w1 * hi16(b2);
        m6 += w1 * lo16(b3); m7 += w1 * hi16(b3);
        m8 += w1 * lo16(b4); m9 += w1 * hi16(b4);
        kacc += w0 * ka + w1 * kb;
    }
    if (e < end) {
        int s0 = src[e];
        float w0 = wgt[e];
        const uint32_t* r0 = Mw + (size_t)s0 * 320 + l;
        uint32_t a0 = r0[0], a1 = r0[64], a2 = r0[128], a3 = r0[192], a4 = r0[256];
        float ka = Ktin[(size_t)s0 * 64 + l];
        m0 += w0 * lo16(a0); m1 += w0 * hi16(a0);
        m2 += w0 * lo16(a1); m3 += w0 * hi16(a1);
        m4 += w0 * lo16(a2); m5 += w0 * hi16(a2);
        m6 += w0 * lo16(a3); m7 += w0 * hi16(a3);
        m8 += w0 * lo16(a4); m9 += w0 * hi16(a4);
        kacc += w0 * ka;
    }

    // stage to LDS (word (l+64c) holds values 2(l+64c), 2(l+64c)+1)
    *(float2*)&Ml[w][2 * l]         = make_float2(m0, m1);
    *(float2*)&Ml[w][2 * (l + 64)]  = make_float2(m2, m3);
    *(float2*)&Ml[w][2 * (l + 128)] = make_float2(m4, m5);
    *(float2*)&Ml[w][2 * (l + 192)] = make_float2(m6, m7);
    *(float2*)&Ml[w][2 * (l + 256)] = make_float2(m8, m9);
    Ktl[w][l] = kacc;
    Ql[w][l] = Q[(size_t)n * 64 + l];
    if constexpr (!LAST) {
        uint32_t* orow = (uint32_t*)Mout + (size_t)n * 320 + l;
        orow[0]   = pack2(m0, m1);
        orow[64]  = pack2(m2, m3);
        orow[128] = pack2(m4, m5);
        orow[192] = pack2(m6, m7);
        orow[256] = pack2(m8, m9);
        Ktout[(size_t)n * 64 + l] = kacc;
    }
    __syncthreads();

    int tt = threadIdx.x;
    if (tt < 160) {
        int ww = tt / 40, o = tt % 40;
        int h = o / 10, j = o % 10;
        const float* q  = &Ql[ww][h * 16];
        const float* kk = &Ktl[ww][h * 16];
        const float* mm = &Ml[ww][h * 160 + j];
        float cd = kCST, hh = 0.f;
#pragma unroll
        for (int i = 0; i < 16; ++i) { cd += q[i] * kk[i]; hh += q[i] * mm[i * 10]; }
        int nn = blockIdx.x * 4 + ww;
        float val = hidden[(size_t)nn * 40 + o] + gammas[h] * hh / cd;
        if constexpr (!LAST) hidden[(size_t)nn * 40 + o] = val;
        else Hl[ww][o] = val;
    }
    if constexpr (LAST) {
        __syncthreads();
        if (tt < 40) {
            int ww = tt / 10, c = tt % 10;
            float acc = b_out[c];
#pragma unroll
            for (int i = 0; i < 40; ++i) acc += Hl[ww][i] * W_out[i * 10 + c];
            out[(size_t)(blockIdx.x * 4 + ww) * 10 + c] = acc;
        }
    }
}

extern "C" void kernel_launch(void* const* d_in, const int* in_sizes, int n_in,
                              void* d_out, int out_size, void* d_ws, size_t ws_size,
                              hipStream_t stream) {
    const float* feat   = (const float*)d_in[0];
    const int*   ei     = (const int*)d_in[1];
    const float* W_in   = (const float*)d_in[2];
    const float* b_in   = (const float*)d_in[3];
    const float* Wq     = (const float*)d_in[4];
    const float* bq     = (const float*)d_in[5];
    const float* Wk     = (const float*)d_in[6];
    const float* bk     = (const float*)d_in[7];
    const float* Wv     = (const float*)d_in[8];
    const float* bv     = (const float*)d_in[9];
    const float* W_out  = (const float*)d_in[10];
    const float* b_out  = (const float*)d_in[11];
    const float* hopwise= (const float*)d_in[12];
    const float* temp   = (const float*)d_in[13];
    float* out = (float*)d_out;

    char* ws = (char*)d_ws;
    size_t off = 0;
    auto alloc = [&](size_t bytes) -> void* {
        void* p = ws + off;
        off += (bytes + 255) & ~(size_t)255;
        return p;
    };
    int*      deg    = (int*)alloc((size_t)kN * 4);
    int*      cursor = (int*)alloc((size_t)kN * 4);
    int*      ptr    = (int*)alloc((size_t)(kN + 1) * 4);
    int*      csrc   = (int*)alloc((size_t)kET * 4);
    float*    cwgt   = (float*)alloc((size_t)kET * 4);
    float*    Q      = (float*)alloc((size_t)kN * kHID * 4);
    float*    Kt0    = (float*)alloc((size_t)kN * kHID * 4);
    float*    Kt1    = (float*)alloc((size_t)kN * kHID * 4);
    float*    hidden = (float*)alloc((size_t)kN * kH * kC * 4);
    float*    gammas = (float*)alloc(64);
    uint16_t* M0     = (uint16_t*)alloc((size_t)kN * 640 * 2);
    uint16_t* M1     = (uint16_t*)alloc((size_t)kN * 640 * 2);
    (void)ws_size; (void)in_sizes; (void)n_in; (void)out_size;

    // deg & cursor are adjacent in ws: one memset covers both
    size_t deg_span = (size_t)((char*)cursor - (char*)deg) + (size_t)kN * 4;
    hipMemsetAsync(deg, 0, deg_span, stream);

    deg_kernel<<<(kET + 255) / 256, 256, 0, stream>>>(ei, deg);
    scan_kernel<<<1, 1024, 0, stream>>>(deg, ptr, hopwise, temp, gammas);
    scatter_kernel<<<(kET + 255) / 256, 256, 0, stream>>>(ei, deg, ptr, cursor, csrc, cwgt);
    fused_qkv_kernel<<<kN / 4, 256, 0, stream>>>(feat, W_in, b_in, Wq, bq, Wk, bk, Wv, bv,
                                                 hopwise, Q, Kt0, hidden, M0);
    hop2_kernel<false><<<kN / 4, 256, 0, stream>>>(ptr, csrc, cwgt, M0, M1, Kt0, Kt1, Q, hidden,
                                                   gammas + 0, W_out, b_out, out);
    hop2_kernel<false><<<kN / 4, 256, 0, stream>>>(ptr, csrc, cwgt, M1, M0, Kt1, Kt0, Q, hidden,
                                                   gammas + 4, W_out, b_out, out);
    hop2_kernel<true><<<kN / 4, 256, 0, stream>>>(ptr, csrc, cwgt, M0, M1, Kt0, Kt1, Q, hidden,
                                                  gammas + 8, W_out, b_out, out);
}

// Round 3
// 221.119 us; speedup vs baseline: 1.8363x; 1.1621x over previous
//
#include <hip/hip_runtime.h>
#include <stdint.h>

// Problem constants (match reference)
#define kN   20000
#define kE   160000
#define kET  (kN + kE)   // edges incl self loops = 180000
#define kF   256
#define kHID 64
#define kH   4
#define kHC  16
#define kC   10
#define kK   3
#define kCST 1e-5f
#define kBN  80          // nodes per proj block (250 blocks exactly)

__device__ __forceinline__ uint16_t f2bf(float x) {
    uint32_t u = __float_as_uint(x);
    u += 0x7fffu + ((u >> 16) & 1u);   // round-to-nearest-even
    return (uint16_t)(u >> 16);
}
__device__ __forceinline__ float lo16(uint32_t p) { return __uint_as_float(p << 16); }
__device__ __forceinline__ float hi16(uint32_t p) { return __uint_as_float(p & 0xffff0000u); }
__device__ __forceinline__ uint32_t pack2(float a, float b) {
    return ((uint32_t)f2bf(b) << 16) | (uint32_t)f2bf(a);
}

// ---- degree histogram over col (incl self loops) ----
__global__ void deg_kernel(const int* __restrict__ ei, int* __restrict__ deg) {
    int e = blockIdx.x * blockDim.x + threadIdx.x;
    if (e >= kET) return;
    int c = (e < kE) ? ei[kE + e] : (e - kE);
    atomicAdd(&deg[c], 1);
}

// ---- single-block scan: deg -> ptr[0..N]; also computes gammas ----
__global__ __launch_bounds__(1024) void scan_kernel(
    const int* __restrict__ deg, int* __restrict__ ptr,
    const float* __restrict__ hopwise, const float* __restrict__ temp,
    float* __restrict__ gammas) {
    __shared__ int wsums[16];
    __shared__ int wexcl[16];
    const int CH = 20;               // 1024*20 = 20480 >= kN
    int t = threadIdx.x;
    int base = t * CH;
    int s = 0;
    for (int i = 0; i < CH; ++i) {
        int idx = base + i;
        if (idx < kN) s += deg[idx];
    }
    int incl = s;
#pragma unroll
    for (int off = 1; off < 64; off <<= 1) {
        int v = __shfl_up(incl, off, 64);
        if ((t & 63) >= off) incl += v;
    }
    int wid = t >> 6;
    if ((t & 63) == 63) wsums[wid] = incl;
    __syncthreads();
    if (t < 16) {
        int p = 0;
        for (int j = 0; j < t; ++j) p += wsums[j];
        wexcl[t] = p;
    }
    __syncthreads();
    int running = wexcl[wid] + incl - s;   // exclusive prefix at `base`
    for (int i = 0; i < CH; ++i) {
        int idx = base + i;
        if (idx < kN) { ptr[idx] = running; running += deg[idx]; }
    }
    if (base < kN && base + CH >= kN) ptr[kN] = running;
    if (t == 0) {
        for (int k = 1; k <= kK; ++k) {
            float mx = -1e30f;
            for (int h = 0; h < kH; ++h) mx = fmaxf(mx, temp[h * (kK + 1) + k]);
            float ex[kH]; float sum = 0.f;
            for (int h = 0; h < kH; ++h) { ex[h] = __expf(temp[h * (kK + 1) + k] - mx); sum += ex[h]; }
            for (int h = 0; h < kH; ++h) gammas[(k - 1) * kH + h] = hopwise[k] * ex[h] / sum;
        }
    }
}

// ---- CSR (by col) build: scatter (row, norm); norm from deg via rsqrt ----
__global__ void scatter_kernel(const int* __restrict__ ei, const int* __restrict__ deg,
                               const int* __restrict__ ptr, int* __restrict__ cursor,
                               int* __restrict__ src, float* __restrict__ wgt) {
    int e = blockIdx.x * blockDim.x + threadIdx.x;
    if (e >= kET) return;
    int r, c;
    if (e < kE) { r = ei[e]; c = ei[kE + e]; } else { r = c = e - kE; }
    float wv = rsqrtf((float)deg[r]) * rsqrtf((float)deg[c]);
    int pos = ptr[c] + atomicAdd(&cursor[c], 1);
    src[pos] = r;
    wgt[pos] = wv;
}

// ---- fused projections, tiled: 80 nodes/block, 256 threads, 5x4 micro-tiles.
//      x = relu(feat@W_in+b); Q/K = 1+elu(x@Wq/Wk+b); V = x@Wv+b;
//      M0 = K outer V (bf16); hidden = V*hopwise[0]; Q,Kt written f32.
__global__ __launch_bounds__(256) void proj_kernel(
    const float* __restrict__ feat, const float* __restrict__ W_in, const float* __restrict__ b_in,
    const float* __restrict__ Wq, const float* __restrict__ bq,
    const float* __restrict__ Wk, const float* __restrict__ bk,
    const float* __restrict__ Wv, const float* __restrict__ bv,
    const float* __restrict__ hopwise,
    float* __restrict__ Qg, float* __restrict__ Ktg, float* __restrict__ hidden,
    uint16_t* __restrict__ M) {
    __shared__ float sA[kBN * 68];   // feat tile -> Wq -> Kt
    __shared__ float sB[64 * 68];    // W_in tile -> Wk -> V
    __shared__ float sX[kBN * 68];   // x
    __shared__ float sWv[64 * 44];   // Wv

    int t = threadIdx.x;
    int tx = t & 15, ty = t >> 4;    // 16 x 16 thread grid
    int n0 = blockIdx.x * kBN;

    // ---- phase 1: x = relu(feat @ W_in + b_in), K-tiled by 64 ----
    float acc[5][4];
#pragma unroll
    for (int i = 0; i < 5; ++i)
#pragma unroll
        for (int j = 0; j < 4; ++j) acc[i][j] = 0.f;

    for (int ks = 0; ks < 4; ++ks) {
        int k0 = ks * 64;
#pragma unroll
        for (int i = 0; i < 5; ++i) {            // 80x16 float4 slots
            int slot = t + 256 * i;
            int row = slot >> 4, cg = slot & 15;
            *(float4*)&sA[row * 68 + cg * 4] =
                *(const float4*)&feat[(size_t)(n0 + row) * kF + k0 + cg * 4];
        }
#pragma unroll
        for (int i = 0; i < 4; ++i) {            // 64x16 float4 slots
            int slot = t + 256 * i;
            int row = slot >> 4, cg = slot & 15;
            *(float4*)&sB[row * 68 + cg * 4] =
                *(const float4*)&W_in[(size_t)(k0 + row) * kHID + cg * 4];
        }
        __syncthreads();
#pragma unroll 8
        for (int kk = 0; kk < 64; ++kk) {
            float4 b = *(float4*)&sB[kk * 68 + tx * 4];
#pragma unroll
            for (int i = 0; i < 5; ++i) {
                float a = sA[(ty * 5 + i) * 68 + kk];
                acc[i][0] += a * b.x; acc[i][1] += a * b.y;
                acc[i][2] += a * b.z; acc[i][3] += a * b.w;
            }
        }
        __syncthreads();
    }
    {
        float bb[4];
#pragma unroll
        for (int j = 0; j < 4; ++j) bb[j] = b_in[tx * 4 + j];
#pragma unroll
        for (int i = 0; i < 5; ++i) {
            float4 xr;
            xr.x = fmaxf(acc[i][0] + bb[0], 0.f);
            xr.y = fmaxf(acc[i][1] + bb[1], 0.f);
            xr.z = fmaxf(acc[i][2] + bb[2], 0.f);
            xr.w = fmaxf(acc[i][3] + bb[3], 0.f);
            *(float4*)&sX[(ty * 5 + i) * 68 + tx * 4] = xr;
        }
    }
    // stage Wq -> sA, Wk -> sB, Wv -> sWv
#pragma unroll
    for (int i = 0; i < 4; ++i) {
        int slot = t + 256 * i;
        int row = slot >> 4, cg = slot & 15;
        *(float4*)&sA[row * 68 + cg * 4] = *(const float4*)&Wq[(size_t)row * kHID + cg * 4];
        *(float4*)&sB[row * 68 + cg * 4] = *(const float4*)&Wk[(size_t)row * kHID + cg * 4];
    }
#pragma unroll
    for (int i = 0; i < 3; ++i) {                // 64x10 float4 slots = 640
        int slot = t + 256 * i;
        if (slot < 640) {
            int row = slot / 10, cg = slot % 10;
            *(float4*)&sWv[row * 44 + cg * 4] = *(const float4*)&Wv[(size_t)row * 40 + cg * 4];
        }
    }
    __syncthreads();

    // ---- phase 2: Q/K = 1+elu(x@Wq/Wk + b) ----
    float qa[5][4], ka[5][4];
#pragma unroll
    for (int i = 0; i < 5; ++i)
#pragma unroll
        for (int j = 0; j < 4; ++j) { qa[i][j] = 0.f; ka[i][j] = 0.f; }
#pragma unroll 4
    for (int kk = 0; kk < 64; ++kk) {
        float4 bq4 = *(float4*)&sA[kk * 68 + tx * 4];
        float4 bk4 = *(float4*)&sB[kk * 68 + tx * 4];
#pragma unroll
        for (int i = 0; i < 5; ++i) {
            float a = sX[(ty * 5 + i) * 68 + kk];
            qa[i][0] += a * bq4.x; qa[i][1] += a * bq4.y;
            qa[i][2] += a * bq4.z; qa[i][3] += a * bq4.w;
            ka[i][0] += a * bk4.x; ka[i][1] += a * bk4.y;
            ka[i][2] += a * bk4.z; ka[i][3] += a * bk4.w;
        }
    }
    {
        float bqv[4], bkv[4];
#pragma unroll
        for (int j = 0; j < 4; ++j) { bqv[j] = bq[tx * 4 + j]; bkv[j] = bk[tx * 4 + j]; }
#pragma unroll
        for (int i = 0; i < 5; ++i) {
            int n = n0 + ty * 5 + i;
            float4 qv, kv;
            float q0 = qa[i][0] + bqv[0], q1 = qa[i][1] + bqv[1];
            float q2 = qa[i][2] + bqv[2], q3 = qa[i][3] + bqv[3];
            qv.x = (q0 > 0.f) ? 1.f + q0 : __expf(q0);
            qv.y = (q1 > 0.f) ? 1.f + q1 : __expf(q1);
            qv.z = (q2 > 0.f) ? 1.f + q2 : __expf(q2);
            qv.w = (q3 > 0.f) ? 1.f + q3 : __expf(q3);
            float k0v = ka[i][0] + bkv[0], k1v = ka[i][1] + bkv[1];
            float k2v = ka[i][2] + bkv[2], k3v = ka[i][3] + bkv[3];
            kv.x = (k0v > 0.f) ? 1.f + k0v : __expf(k0v);
            kv.y = (k1v > 0.f) ? 1.f + k1v : __expf(k1v);
            kv.z = (k2v > 0.f) ? 1.f + k2v : __expf(k2v);
            kv.w = (k3v > 0.f) ? 1.f + k3v : __expf(k3v);
            ka[i][0] = kv.x; ka[i][1] = kv.y; ka[i][2] = kv.z; ka[i][3] = kv.w;
            *(float4*)&Qg[(size_t)n * kHID + tx * 4] = qv;
            *(float4*)&Ktg[(size_t)n * kHID + tx * 4] = kv;
        }
    }
    __syncthreads();   // everyone done reading sA/sB

    // Kt -> sA (for phase 3)
#pragma unroll
    for (int i = 0; i < 5; ++i) {
        float4 kv = make_float4(ka[i][0], ka[i][1], ka[i][2], ka[i][3]);
        *(float4*)&sA[(ty * 5 + i) * 68 + tx * 4] = kv;
    }
    // ---- phase 2b: V = x@Wv + b (threads 0..159: 16 row-groups x 10 col-groups) ----
    if (t < 160) {
        int txv = t % 10, tyv = t / 10;
        float va[5][4];
#pragma unroll
        for (int i = 0; i < 5; ++i)
#pragma unroll
            for (int j = 0; j < 4; ++j) va[i][j] = 0.f;
#pragma unroll 4
        for (int kk = 0; kk < 64; ++kk) {
            float4 bv4 = *(float4*)&sWv[kk * 44 + txv * 4];
#pragma unroll
            for (int i = 0; i < 5; ++i) {
                float a = sX[(tyv * 5 + i) * 68 + kk];
                va[i][0] += a * bv4.x; va[i][1] += a * bv4.y;
                va[i][2] += a * bv4.z; va[i][3] += a * bv4.w;
            }
        }
        float bvv[4];
#pragma unroll
        for (int j = 0; j < 4; ++j) bvv[j] = bv[txv * 4 + j];
        float hw0 = hopwise[0];
#pragma unroll
        for (int i = 0; i < 5; ++i) {
            int row = tyv * 5 + i;
            float4 vr;
            vr.x = va[i][0] + bvv[0]; vr.y = va[i][1] + bvv[1];
            vr.z = va[i][2] + bvv[2]; vr.w = va[i][3] + bvv[3];
            *(float4*)&sB[row * 44 + txv * 4] = vr;
            float4 hr;
            hr.x = vr.x * hw0; hr.y = vr.y * hw0; hr.z = vr.z * hw0; hr.w = vr.w * hw0;
            *(float4*)&hidden[(size_t)(n0 + row) * 40 + txv * 4] = hr;
        }
    }
    __syncthreads();

    // ---- phase 3: M[n,h,i,c] = Kt[n,h,i]*V[n,h,c] -> bf16, canonical row-major pairs ----
    int w = t >> 6, l = t & 63, h = l >> 4;
    uint32_t* Mw = (uint32_t*)M;
#pragma unroll 2
    for (int it = 0; it < 20; ++it) {
        int node = it * 4 + w;
        float kt = sA[node * 68 + l];
        const float* vp = &sB[node * 44 + h * 10];
        uint32_t* dst = Mw + (size_t)(n0 + node) * 320 + l * 5;
#pragma unroll
        for (int j = 0; j < 5; ++j)
            dst[j] = pack2(kt * vp[2 * j], kt * vp[2 * j + 1]);
    }
}

// ---- one hop, wave-per-node: gather M (bf16, 5 words/lane) & Kt (1 f32/lane),
//      unrolled x2 edges for MLP; epilogue computes Hh/Cd update.
//      LAST: skip M/Kt writeback, fuse output GEMM.
template<bool LAST>
__global__ __launch_bounds__(256) void hop2_kernel(
    const int* __restrict__ ptr, const int* __restrict__ src, const float* __restrict__ wgt,
    const uint16_t* __restrict__ Min, uint16_t* __restrict__ Mout,
    const float* __restrict__ Ktin, float* __restrict__ Ktout,
    const float* __restrict__ Q, float* __restrict__ hidden,
    const float* __restrict__ gammas,
    const float* __restrict__ W_out, const float* __restrict__ b_out,
    float* __restrict__ out) {
    __shared__ float Ml[4][640];
    __shared__ float Ktl[4][64];
    __shared__ float Ql[4][64];
    __shared__ float Hl[4][40];
    int w = threadIdx.x >> 6;     // node slot
    int l = threadIdx.x & 63;     // lane
    int n = blockIdx.x * 4 + w;
    int beg = ptr[n], end = ptr[n + 1];
    const uint32_t* Mw = (const uint32_t*)Min;

    float m0=0,m1=0,m2=0,m3=0,m4=0,m5=0,m6=0,m7=0,m8=0,m9=0;
    float kacc = 0.f;
    int e = beg;
    for (; e + 2 <= end; e += 2) {
        int s0 = src[e], s1 = src[e + 1];
        float w0 = wgt[e], w1 = wgt[e + 1];
        const uint32_t* r0 = Mw + (size_t)s0 * 320 + l;
        const uint32_t* r1 = Mw + (size_t)s1 * 320 + l;
        uint32_t a0 = r0[0], a1 = r0[64], a2 = r0[128], a3 = r0[192], a4 = r0[256];
        uint32_t b0 = r1[0], b1 = r1[64], b2 = r1[128], b3 = r1[192], b4 = r1[256];
        float ka = Ktin[(size_t)s0 * 64 + l], kb = Ktin[(size_t)s1 * 64 + l];
        m0 += w0 * lo16(a0); m1 += w0 * hi16(a0);
        m2 += w0 * lo16(a1); m3 += w0 * hi16(a1);
        m4 += w0 * lo16(a2); m5 += w0 * hi16(a2);
        m6 += w0 * lo16(a3); m7 += w0 * hi16(a3);
        m8 += w0 * lo16(a4); m9 += w0 * hi16(a4);
        m0 += w1 * lo16(b0); m1 += w1 * hi16(b0);
        m2 += w1 * lo16(b1); m3 += w1 * hi16(b1);
        m4 += w1 * lo16(b2); m5 += w1 * hi16(b2);
        m6 += w1 * lo16(b3); m7 += w1 * hi16(b3);
        m8 += w1 * lo16(b4); m9 += w1 * hi16(b4);
        kacc += w0 * ka + w1 * kb;
    }
    if (e < end) {
        int s0 = src[e];
        float w0 = wgt[e];
        const uint32_t* r0 = Mw + (size_t)s0 * 320 + l;
        uint32_t a0 = r0[0], a1 = r0[64], a2 = r0[128], a3 = r0[192], a4 = r0[256];
        float ka = Ktin[(size_t)s0 * 64 + l];
        m0 += w0 * lo16(a0); m1 += w0 * hi16(a0);
        m2 += w0 * lo16(a1); m3 += w0 * hi16(a1);
        m4 += w0 * lo16(a2); m5 += w0 * hi16(a2);
        m6 += w0 * lo16(a3); m7 += w0 * hi16(a3);
        m8 += w0 * lo16(a4); m9 += w0 * hi16(a4);
        kacc += w0 * ka;
    }

    // stage to LDS (word (l+64c) holds values 2(l+64c), 2(l+64c)+1)
    *(float2*)&Ml[w][2 * l]         = make_float2(m0, m1);
    *(float2*)&Ml[w][2 * (l + 64)]  = make_float2(m2, m3);
    *(float2*)&Ml[w][2 * (l + 128)] = make_float2(m4, m5);
    *(float2*)&Ml[w][2 * (l + 192)] = make_float2(m6, m7);
    *(float2*)&Ml[w][2 * (l + 256)] = make_float2(m8, m9);
    Ktl[w][l] = kacc;
    Ql[w][l] = Q[(size_t)n * 64 + l];
    if constexpr (!LAST) {
        uint32_t* orow = (uint32_t*)Mout + (size_t)n * 320 + l;
        orow[0]   = pack2(m0, m1);
        orow[64]  = pack2(m2, m3);
        orow[128] = pack2(m4, m5);
        orow[192] = pack2(m6, m7);
        orow[256] = pack2(m8, m9);
        Ktout[(size_t)n * 64 + l] = kacc;
    }
    __syncthreads();

    int tt = threadIdx.x;
    if (tt < 160) {
        int ww = tt / 40, o = tt % 40;
        int h = o / 10, j = o % 10;
        const float* q  = &Ql[ww][h * 16];
        const float* kk = &Ktl[ww][h * 16];
        const float* mm = &Ml[ww][h * 160 + j];
        float cd = kCST, hh = 0.f;
#pragma unroll
        for (int i = 0; i < 16; ++i) { cd += q[i] * kk[i]; hh += q[i] * mm[i * 10]; }
        int nn = blockIdx.x * 4 + ww;
        float val = hidden[(size_t)nn * 40 + o] + gammas[h] * hh / cd;
        if constexpr (!LAST) hidden[(size_t)nn * 40 + o] = val;
        else Hl[ww][o] = val;
    }
    if constexpr (LAST) {
        __syncthreads();
        if (tt < 40) {
            int ww = tt / 10, c = tt % 10;
            float acc = b_out[c];
#pragma unroll
            for (int i = 0; i < 40; ++i) acc += Hl[ww][i] * W_out[i * 10 + c];
            out[(size_t)(blockIdx.x * 4 + ww) * 10 + c] = acc;
        }
    }
}

extern "C" void kernel_launch(void* const* d_in, const int* in_sizes, int n_in,
                              void* d_out, int out_size, void* d_ws, size_t ws_size,
                              hipStream_t stream) {
    const float* feat   = (const float*)d_in[0];
    const int*   ei     = (const int*)d_in[1];
    const float* W_in   = (const float*)d_in[2];
    const float* b_in   = (const float*)d_in[3];
    const float* Wq     = (const float*)d_in[4];
    const float* bq     = (const float*)d_in[5];
    const float* Wk     = (const float*)d_in[6];
    const float* bk     = (const float*)d_in[7];
    const float* Wv     = (const float*)d_in[8];
    const float* bv     = (const float*)d_in[9];
    const float* W_out  = (const float*)d_in[10];
    const float* b_out  = (const float*)d_in[11];
    const float* hopwise= (const float*)d_in[12];
    const float* temp   = (const float*)d_in[13];
    float* out = (float*)d_out;

    char* ws = (char*)d_ws;
    size_t off = 0;
    auto alloc = [&](size_t bytes) -> void* {
        void* p = ws + off;
        off += (bytes + 255) & ~(size_t)255;
        return p;
    };
    int*      deg    = (int*)alloc((size_t)kN * 4);
    int*      cursor = (int*)alloc((size_t)kN * 4);
    int*      ptr    = (int*)alloc((size_t)(kN + 1) * 4);
    int*      csrc   = (int*)alloc((size_t)kET * 4);
    float*    cwgt   = (float*)alloc((size_t)kET * 4);
    float*    Q      = (float*)alloc((size_t)kN * kHID * 4);
    float*    Kt0    = (float*)alloc((size_t)kN * kHID * 4);
    float*    Kt1    = (float*)alloc((size_t)kN * kHID * 4);
    float*    hidden = (float*)alloc((size_t)kN * kH * kC * 4);
    float*    gammas = (float*)alloc(64);
    uint16_t* M0     = (uint16_t*)alloc((size_t)kN * 640 * 2);
    uint16_t* M1     = (uint16_t*)alloc((size_t)kN * 640 * 2);
    (void)ws_size; (void)in_sizes; (void)n_in; (void)out_size;

    // deg & cursor are adjacent in ws: one memset covers both
    size_t deg_span = (size_t)((char*)cursor - (char*)deg) + (size_t)kN * 4;
    hipMemsetAsync(deg, 0, deg_span, stream);

    deg_kernel<<<(kET + 255) / 256, 256, 0, stream>>>(ei, deg);
    scan_kernel<<<1, 1024, 0, stream>>>(deg, ptr, hopwise, temp, gammas);
    scatter_kernel<<<(kET + 255) / 256, 256, 0, stream>>>(ei, deg, ptr, cursor, csrc, cwgt);
    proj_kernel<<<kN / kBN, 256, 0, stream>>>(feat, W_in, b_in, Wq, bq, Wk, bk, Wv, bv,
                                              hopwise, Q, Kt0, hidden, M0);
    hop2_kernel<false><<<kN / 4, 256, 0, stream>>>(ptr, csrc, cwgt, M0, M1, Kt0, Kt1, Q, hidden,
                                                   gammas + 0, W_out, b_out, out);
    hop2_kernel<false><<<kN / 4, 256, 0, stream>>>(ptr, csrc, cwgt, M1, M0, Kt1, Kt0, Q, hidden,
                                                   gammas + 4, W_out, b_out, out);
    hop2_kernel<true><<<kN / 4, 256, 0, stream>>>(ptr, csrc, cwgt, M0, M1, Kt0, Kt1, Q, hidden,
                                                  gammas + 8, W_out, b_out, out);
}

// Round 4
// 211.171 us; speedup vs baseline: 1.9229x; 1.0471x over previous
//
#include <hip/hip_runtime.h>
#include <stdint.h>

// Problem constants (match reference)
#define kN   20000
#define kE   160000
#define kET  (kN + kE)   // edges incl self loops = 180000
#define kF   256
#define kHID 64
#define kH   4
#define kHC  16
#define kC   10
#define kK   3
#define kCST 1e-5f
#define kBN  32          // nodes per proj block (625 blocks)

__device__ __forceinline__ uint16_t f2bf(float x) {
    uint32_t u = __float_as_uint(x);
    u += 0x7fffu + ((u >> 16) & 1u);   // round-to-nearest-even
    return (uint16_t)(u >> 16);
}
__device__ __forceinline__ float lo16(uint32_t p) { return __uint_as_float(p << 16); }
__device__ __forceinline__ float hi16(uint32_t p) { return __uint_as_float(p & 0xffff0000u); }
__device__ __forceinline__ uint32_t pack2(float a, float b) {
    return ((uint32_t)f2bf(b) << 16) | (uint32_t)f2bf(a);
}

// ---- degree histogram over col (incl self loops) ----
__global__ void deg_kernel(const int* __restrict__ ei, int* __restrict__ deg) {
    int e = blockIdx.x * blockDim.x + threadIdx.x;
    if (e >= kET) return;
    int c = (e < kE) ? ei[kE + e] : (e - kE);
    atomicAdd(&deg[c], 1);
}

// ---- single-block scan: deg -> ptr[0..N]; also computes gammas ----
__global__ __launch_bounds__(1024) void scan_kernel(
    const int* __restrict__ deg, int* __restrict__ ptr,
    const float* __restrict__ hopwise, const float* __restrict__ temp,
    float* __restrict__ gammas) {
    __shared__ int wsums[16];
    __shared__ int wexcl[16];
    const int CH = 20;               // 1024*20 = 20480 >= kN
    int t = threadIdx.x;
    int base = t * CH;
    int s = 0;
    for (int i = 0; i < CH; ++i) {
        int idx = base + i;
        if (idx < kN) s += deg[idx];
    }
    int incl = s;
#pragma unroll
    for (int off = 1; off < 64; off <<= 1) {
        int v = __shfl_up(incl, off, 64);
        if ((t & 63) >= off) incl += v;
    }
    int wid = t >> 6;
    if ((t & 63) == 63) wsums[wid] = incl;
    __syncthreads();
    if (t < 16) {
        int p = 0;
        for (int j = 0; j < t; ++j) p += wsums[j];
        wexcl[t] = p;
    }
    __syncthreads();
    int running = wexcl[wid] + incl - s;   // exclusive prefix at `base`
    for (int i = 0; i < CH; ++i) {
        int idx = base + i;
        if (idx < kN) { ptr[idx] = running; running += deg[idx]; }
    }
    if (base < kN && base + CH >= kN) ptr[kN] = running;
    if (t == 0) {
        for (int k = 1; k <= kK; ++k) {
            float mx = -1e30f;
            for (int h = 0; h < kH; ++h) mx = fmaxf(mx, temp[h * (kK + 1) + k]);
            float ex[kH]; float sum = 0.f;
            for (int h = 0; h < kH; ++h) { ex[h] = __expf(temp[h * (kK + 1) + k] - mx); sum += ex[h]; }
            for (int h = 0; h < kH; ++h) gammas[(k - 1) * kH + h] = hopwise[k] * ex[h] / sum;
        }
    }
}

// ---- CSR (by col) build: scatter (row, norm); norm from deg via rsqrt ----
__global__ void scatter_kernel(const int* __restrict__ ei, const int* __restrict__ deg,
                               const int* __restrict__ ptr, int* __restrict__ cursor,
                               int* __restrict__ src, float* __restrict__ wgt) {
    int e = blockIdx.x * blockDim.x + threadIdx.x;
    if (e >= kET) return;
    int r, c;
    if (e < kE) { r = ei[e]; c = ei[kE + e]; } else { r = c = e - kE; }
    float wv = rsqrtf((float)deg[r]) * rsqrtf((float)deg[c]);
    int pos = ptr[c] + atomicAdd(&cursor[c], 1);
    src[pos] = r;
    wgt[pos] = wv;
}

// ---- fused projections, 32 nodes/block x 625 blocks, ~41 KB LDS.
//      x = relu(feat@W_in+b); Q/K = 1+elu(x@Wq/Wk+b); V = x@Wv+b;
//      M0 = K outer V (bf16, canonical word p = values 2p,2p+1);
//      hidden = V*hopwise[0]; Q,Kt f32 to global.
__global__ __launch_bounds__(256) void proj_kernel(
    const float* __restrict__ feat, const float* __restrict__ W_in, const float* __restrict__ b_in,
    const float* __restrict__ Wq, const float* __restrict__ bq,
    const float* __restrict__ Wk, const float* __restrict__ bk,
    const float* __restrict__ Wv, const float* __restrict__ bv,
    const float* __restrict__ hopwise,
    float* __restrict__ Qg, float* __restrict__ Ktg, float* __restrict__ hidden,
    uint16_t* __restrict__ M) {
    __shared__ float sF[kBN * 68];   // feat k-tile, later Kt
    __shared__ float sW[64 * 68];    // W_in tile -> Wq -> Wk -> Wv
    __shared__ float sX[kBN * 68];   // x
    __shared__ float sV[kBN * 44];   // V

    int t = threadIdx.x;
    int tx = t & 15, ty = t >> 4;    // 16 x 16 thread grid
    int n0 = blockIdx.x * kBN;
    int r0 = ty * 2, r1 = ty * 2 + 1;

    // ---- phase 1: x = relu(feat @ W_in + b_in), K tiled by 64 ----
    float acc[2][4];
#pragma unroll
    for (int i = 0; i < 2; ++i)
#pragma unroll
        for (int j = 0; j < 4; ++j) acc[i][j] = 0.f;

    for (int ks = 0; ks < 4; ++ks) {
        int k0 = ks * 64;
#pragma unroll
        for (int i = 0; i < 2; ++i) {            // 32x16 float4 slots = 512
            int slot = t + 256 * i;
            int row = slot >> 4, cg = slot & 15;
            *(float4*)&sF[row * 68 + cg * 4] =
                *(const float4*)&feat[(size_t)(n0 + row) * kF + k0 + cg * 4];
        }
#pragma unroll
        for (int i = 0; i < 4; ++i) {            // 64x16 float4 slots = 1024
            int slot = t + 256 * i;
            int row = slot >> 4, cg = slot & 15;
            *(float4*)&sW[row * 68 + cg * 4] =
                *(const float4*)&W_in[(size_t)(k0 + row) * kHID + cg * 4];
        }
        __syncthreads();
#pragma unroll 8
        for (int kk = 0; kk < 64; ++kk) {
            float4 b = *(float4*)&sW[kk * 68 + tx * 4];
            float a0 = sF[r0 * 68 + kk], a1 = sF[r1 * 68 + kk];
            acc[0][0] += a0 * b.x; acc[0][1] += a0 * b.y;
            acc[0][2] += a0 * b.z; acc[0][3] += a0 * b.w;
            acc[1][0] += a1 * b.x; acc[1][1] += a1 * b.y;
            acc[1][2] += a1 * b.z; acc[1][3] += a1 * b.w;
        }
        __syncthreads();
    }
    {
        float bb[4];
#pragma unroll
        for (int j = 0; j < 4; ++j) bb[j] = b_in[tx * 4 + j];
#pragma unroll
        for (int i = 0; i < 2; ++i) {
            float4 xr;
            xr.x = fmaxf(acc[i][0] + bb[0], 0.f);
            xr.y = fmaxf(acc[i][1] + bb[1], 0.f);
            xr.z = fmaxf(acc[i][2] + bb[2], 0.f);
            xr.w = fmaxf(acc[i][3] + bb[3], 0.f);
            *(float4*)&sX[(r0 + i) * 68 + tx * 4] = xr;
        }
    }
    // stage Wq (sW free after last barrier above)
#pragma unroll
    for (int i = 0; i < 4; ++i) {
        int slot = t + 256 * i;
        int row = slot >> 4, cg = slot & 15;
        *(float4*)&sW[row * 68 + cg * 4] = *(const float4*)&Wq[(size_t)row * kHID + cg * 4];
    }
    __syncthreads();

    // ---- Q pass ----
    float qa[2][4];
#pragma unroll
    for (int i = 0; i < 2; ++i)
#pragma unroll
        for (int j = 0; j < 4; ++j) qa[i][j] = 0.f;
#pragma unroll 8
    for (int kk = 0; kk < 64; ++kk) {
        float4 b = *(float4*)&sW[kk * 68 + tx * 4];
        float a0 = sX[r0 * 68 + kk], a1 = sX[r1 * 68 + kk];
        qa[0][0] += a0 * b.x; qa[0][1] += a0 * b.y;
        qa[0][2] += a0 * b.z; qa[0][3] += a0 * b.w;
        qa[1][0] += a1 * b.x; qa[1][1] += a1 * b.y;
        qa[1][2] += a1 * b.z; qa[1][3] += a1 * b.w;
    }
    {
        float bqv[4];
#pragma unroll
        for (int j = 0; j < 4; ++j) bqv[j] = bq[tx * 4 + j];
#pragma unroll
        for (int i = 0; i < 2; ++i) {
            float4 qv;
            float q0 = qa[i][0] + bqv[0], q1 = qa[i][1] + bqv[1];
            float q2 = qa[i][2] + bqv[2], q3 = qa[i][3] + bqv[3];
            qv.x = (q0 > 0.f) ? 1.f + q0 : __expf(q0);
            qv.y = (q1 > 0.f) ? 1.f + q1 : __expf(q1);
            qv.z = (q2 > 0.f) ? 1.f + q2 : __expf(q2);
            qv.w = (q3 > 0.f) ? 1.f + q3 : __expf(q3);
            *(float4*)&Qg[(size_t)(n0 + r0 + i) * kHID + tx * 4] = qv;
        }
    }
    __syncthreads();
    // stage Wk
#pragma unroll
    for (int i = 0; i < 4; ++i) {
        int slot = t + 256 * i;
        int row = slot >> 4, cg = slot & 15;
        *(float4*)&sW[row * 68 + cg * 4] = *(const float4*)&Wk[(size_t)row * kHID + cg * 4];
    }
    __syncthreads();

    // ---- K pass ----
    float ka[2][4];
#pragma unroll
    for (int i = 0; i < 2; ++i)
#pragma unroll
        for (int j = 0; j < 4; ++j) ka[i][j] = 0.f;
#pragma unroll 8
    for (int kk = 0; kk < 64; ++kk) {
        float4 b = *(float4*)&sW[kk * 68 + tx * 4];
        float a0 = sX[r0 * 68 + kk], a1 = sX[r1 * 68 + kk];
        ka[0][0] += a0 * b.x; ka[0][1] += a0 * b.y;
        ka[0][2] += a0 * b.z; ka[0][3] += a0 * b.w;
        ka[1][0] += a1 * b.x; ka[1][1] += a1 * b.y;
        ka[1][2] += a1 * b.z; ka[1][3] += a1 * b.w;
    }
    {
        float bkv[4];
#pragma unroll
        for (int j = 0; j < 4; ++j) bkv[j] = bk[tx * 4 + j];
#pragma unroll
        for (int i = 0; i < 2; ++i) {
            float4 kv;
            float k0v = ka[i][0] + bkv[0], k1v = ka[i][1] + bkv[1];
            float k2v = ka[i][2] + bkv[2], k3v = ka[i][3] + bkv[3];
            kv.x = (k0v > 0.f) ? 1.f + k0v : __expf(k0v);
            kv.y = (k1v > 0.f) ? 1.f + k1v : __expf(k1v);
            kv.z = (k2v > 0.f) ? 1.f + k2v : __expf(k2v);
            kv.w = (k3v > 0.f) ? 1.f + k3v : __expf(k3v);
            *(float4*)&Ktg[(size_t)(n0 + r0 + i) * kHID + tx * 4] = kv;
            *(float4*)&sF[(r0 + i) * 68 + tx * 4] = kv;   // Kt into sF (feat tile dead)
        }
    }
    __syncthreads();
    // stage Wv as [64][44] (640 float4 slots)
#pragma unroll
    for (int i = 0; i < 3; ++i) {
        int slot = t + 256 * i;
        if (slot < 640) {
            int row = slot / 10, cg = slot % 10;
            *(float4*)&sW[row * 44 + cg * 4] = *(const float4*)&Wv[(size_t)row * 40 + cg * 4];
        }
    }
    __syncthreads();

    // ---- V pass (threads 0..159: 16 row-groups x 10 col-groups) ----
    if (t < 160) {
        int txv = t % 10, tyv = t / 10;
        int vr0 = tyv * 2;
        float va[2][4];
#pragma unroll
        for (int i = 0; i < 2; ++i)
#pragma unroll
            for (int j = 0; j < 4; ++j) va[i][j] = 0.f;
#pragma unroll 8
        for (int kk = 0; kk < 64; ++kk) {
            float4 b = *(float4*)&sW[kk * 44 + txv * 4];
            float a0 = sX[vr0 * 68 + kk], a1 = sX[(vr0 + 1) * 68 + kk];
            va[0][0] += a0 * b.x; va[0][1] += a0 * b.y;
            va[0][2] += a0 * b.z; va[0][3] += a0 * b.w;
            va[1][0] += a1 * b.x; va[1][1] += a1 * b.y;
            va[1][2] += a1 * b.z; va[1][3] += a1 * b.w;
        }
        float bvv[4];
#pragma unroll
        for (int j = 0; j < 4; ++j) bvv[j] = bv[txv * 4 + j];
        float hw0 = hopwise[0];
#pragma unroll
        for (int i = 0; i < 2; ++i) {
            int row = vr0 + i;
            float4 vr;
            vr.x = va[i][0] + bvv[0]; vr.y = va[i][1] + bvv[1];
            vr.z = va[i][2] + bvv[2]; vr.w = va[i][3] + bvv[3];
            *(float4*)&sV[row * 44 + txv * 4] = vr;
            float4 hr;
            hr.x = vr.x * hw0; hr.y = vr.y * hw0; hr.z = vr.z * hw0; hr.w = vr.w * hw0;
            *(float4*)&hidden[(size_t)(n0 + row) * 40 + txv * 4] = hr;
        }
    }
    __syncthreads();

    // ---- M phase: canonical word p holds values (2p, 2p+1); plane-coalesced stores.
    //      word p: h=p/80, i=(p%80)/5, j=p%5 -> Kt[h*16+i] * V[h*10+2j(+1)]
    int w = t >> 6, l = t & 63;
    uint32_t* Mw = (uint32_t*)M;
    int offK[5], offV[5];
#pragma unroll
    for (int c = 0; c < 5; ++c) {
        int p = l + 64 * c;
        int h = p / 80, r5 = p - h * 80;
        int i = r5 / 5, j = r5 - i * 5;
        offK[c] = h * 16 + i;
        offV[c] = h * 10 + 2 * j;
    }
#pragma unroll 2
    for (int it = 0; it < 8; ++it) {
        int node = it * 4 + w;
        uint32_t* dst = Mw + (size_t)(n0 + node) * 320 + l;
        const float* kb = &sF[node * 68];
        const float* vb = &sV[node * 44];
#pragma unroll
        for (int c = 0; c < 5; ++c) {
            float kt = kb[offK[c]];
            dst[64 * c] = pack2(kt * vb[offV[c]], kt * vb[offV[c] + 1]);
        }
    }
}

// ---- one hop, wave-per-node: gather M (bf16, 5 words/lane) & Kt (1 f32/lane),
//      4-edge unroll for MLP; epilogue computes Hh/Cd update.
//      LAST: skip M/Kt writeback, fuse output GEMM.
template<bool LAST>
__global__ __launch_bounds__(256) void hop2_kernel(
    const int* __restrict__ ptr, const int* __restrict__ src, const float* __restrict__ wgt,
    const uint16_t* __restrict__ Min, uint16_t* __restrict__ Mout,
    const float* __restrict__ Ktin, float* __restrict__ Ktout,
    const float* __restrict__ Q, float* __restrict__ hidden,
    const float* __restrict__ gammas,
    const float* __restrict__ W_out, const float* __restrict__ b_out,
    float* __restrict__ out) {
    __shared__ float Ml[4][640];
    __shared__ float Ktl[4][64];
    __shared__ float Ql[4][64];
    __shared__ float Hl[4][40];
    int w = threadIdx.x >> 6;     // node slot
    int l = threadIdx.x & 63;     // lane
    int n = blockIdx.x * 4 + w;
    int beg = ptr[n], end = ptr[n + 1];
    const uint32_t* Mw = (const uint32_t*)Min;

    Ql[w][l] = Q[(size_t)n * 64 + l];   // hoisted: overlaps with gather

    float m0=0,m1=0,m2=0,m3=0,m4=0,m5=0,m6=0,m7=0,m8=0,m9=0;
    float kacc = 0.f;
    int e = beg;
    for (; e + 4 <= end; e += 4) {
        int s0 = src[e], s1 = src[e + 1], s2 = src[e + 2], s3 = src[e + 3];
        float w0 = wgt[e], w1 = wgt[e + 1], w2 = wgt[e + 2], w3 = wgt[e + 3];
        const uint32_t* p0 = Mw + (size_t)s0 * 320 + l;
        const uint32_t* p1 = Mw + (size_t)s1 * 320 + l;
        const uint32_t* p2 = Mw + (size_t)s2 * 320 + l;
        const uint32_t* p3 = Mw + (size_t)s3 * 320 + l;
        uint32_t a0 = p0[0], a1 = p0[64], a2 = p0[128], a3 = p0[192], a4 = p0[256];
        uint32_t b0 = p1[0], b1 = p1[64], b2 = p1[128], b3 = p1[192], b4 = p1[256];
        uint32_t c0 = p2[0], c1 = p2[64], c2 = p2[128], c3 = p2[192], c4 = p2[256];
        uint32_t d0 = p3[0], d1 = p3[64], d2 = p3[128], d3 = p3[192], d4 = p3[256];
        float ka = Ktin[(size_t)s0 * 64 + l], kb = Ktin[(size_t)s1 * 64 + l];
        float kc = Ktin[(size_t)s2 * 64 + l], kd = Ktin[(size_t)s3 * 64 + l];
        m0 += w0 * lo16(a0); m1 += w0 * hi16(a0);
        m2 += w0 * lo16(a1); m3 += w0 * hi16(a1);
        m4 += w0 * lo16(a2); m5 += w0 * hi16(a2);
        m6 += w0 * lo16(a3); m7 += w0 * hi16(a3);
        m8 += w0 * lo16(a4); m9 += w0 * hi16(a4);
        m0 += w1 * lo16(b0); m1 += w1 * hi16(b0);
        m2 += w1 * lo16(b1); m3 += w1 * hi16(b1);
        m4 += w1 * lo16(b2); m5 += w1 * hi16(b2);
        m6 += w1 * lo16(b3); m7 += w1 * hi16(b3);
        m8 += w1 * lo16(b4); m9 += w1 * hi16(b4);
        m0 += w2 * lo16(c0); m1 += w2 * hi16(c0);
        m2 += w2 * lo16(c1); m3 += w2 * hi16(c1);
        m4 += w2 * lo16(c2); m5 += w2 * hi16(c2);
        m6 += w2 * lo16(c3); m7 += w2 * hi16(c3);
        m8 += w2 * lo16(c4); m9 += w2 * hi16(c4);
        m0 += w3 * lo16(d0); m1 += w3 * hi16(d0);
        m2 += w3 * lo16(d1); m3 += w3 * hi16(d1);
        m4 += w3 * lo16(d2); m5 += w3 * hi16(d2);
        m6 += w3 * lo16(d3); m7 += w3 * hi16(d3);
        m8 += w3 * lo16(d4); m9 += w3 * hi16(d4);
        kacc += w0 * ka + w1 * kb + w2 * kc + w3 * kd;
    }
    for (; e + 2 <= end; e += 2) {
        int s0 = src[e], s1 = src[e + 1];
        float w0 = wgt[e], w1 = wgt[e + 1];
        const uint32_t* p0 = Mw + (size_t)s0 * 320 + l;
        const uint32_t* p1 = Mw + (size_t)s1 * 320 + l;
        uint32_t a0 = p0[0], a1 = p0[64], a2 = p0[128], a3 = p0[192], a4 = p0[256];
        uint32_t b0 = p1[0], b1 = p1[64], b2 = p1[128], b3 = p1[192], b4 = p1[256];
        float ka = Ktin[(size_t)s0 * 64 + l], kb = Ktin[(size_t)s1 * 64 + l];
        m0 += w0 * lo16(a0); m1 += w0 * hi16(a0);
        m2 += w0 * lo16(a1); m3 += w0 * hi16(a1);
        m4 += w0 * lo16(a2); m5 += w0 * hi16(a2);
        m6 += w0 * lo16(a3); m7 += w0 * hi16(a3);
        m8 += w0 * lo16(a4); m9 += w0 * hi16(a4);
        m0 += w1 * lo16(b0); m1 += w1 * hi16(b0);
        m2 += w1 * lo16(b1); m3 += w1 * hi16(b1);
        m4 += w1 * lo16(b2); m5 += w1 * hi16(b2);
        m6 += w1 * lo16(b3); m7 += w1 * hi16(b3);
        m8 += w1 * lo16(b4); m9 += w1 * hi16(b4);
        kacc += w0 * ka + w1 * kb;
    }
    if (e < end) {
        int s0 = src[e];
        float w0 = wgt[e];
        const uint32_t* p0 = Mw + (size_t)s0 * 320 + l;
        uint32_t a0 = p0[0], a1 = p0[64], a2 = p0[128], a3 = p0[192], a4 = p0[256];
        float ka = Ktin[(size_t)s0 * 64 + l];
        m0 += w0 * lo16(a0); m1 += w0 * hi16(a0);
        m2 += w0 * lo16(a1); m3 += w0 * hi16(a1);
        m4 += w0 * lo16(a2); m5 += w0 * hi16(a2);
        m6 += w0 * lo16(a3); m7 += w0 * hi16(a3);
        m8 += w0 * lo16(a4); m9 += w0 * hi16(a4);
        kacc += w0 * ka;
    }

    // stage to LDS (word (l+64c) holds values 2(l+64c), 2(l+64c)+1)
    *(float2*)&Ml[w][2 * l]         = make_float2(m0, m1);
    *(float2*)&Ml[w][2 * (l + 64)]  = make_float2(m2, m3);
    *(float2*)&Ml[w][2 * (l + 128)] = make_float2(m4, m5);
    *(float2*)&Ml[w][2 * (l + 192)] = make_float2(m6, m7);
    *(float2*)&Ml[w][2 * (l + 256)] = make_float2(m8, m9);
    Ktl[w][l] = kacc;
    if constexpr (!LAST) {
        uint32_t* orow = (uint32_t*)Mout + (size_t)n * 320 + l;
        orow[0]   = pack2(m0, m1);
        orow[64]  = pack2(m2, m3);
        orow[128] = pack2(m4, m5);
        orow[192] = pack2(m6, m7);
        orow[256] = pack2(m8, m9);
        Ktout[(size_t)n * 64 + l] = kacc;
    }
    __syncthreads();

    int tt = threadIdx.x;
    if (tt < 160) {
        int ww = tt / 40, o = tt % 40;
        int h = o / 10, j = o % 10;
        const float* q  = &Ql[ww][h * 16];
        const float* kk = &Ktl[ww][h * 16];
        const float* mm = &Ml[ww][h * 160 + j];
        float cd = kCST, hh = 0.f;
#pragma unroll
        for (int i = 0; i < 16; ++i) { cd += q[i] * kk[i]; hh += q[i] * mm[i * 10]; }
        int nn = blockIdx.x * 4 + ww;
        float val = hidden[(size_t)nn * 40 + o] + gammas[h] * hh / cd;
        if constexpr (!LAST) hidden[(size_t)nn * 40 + o] = val;
        else Hl[ww][o] = val;
    }
    if constexpr (LAST) {
        __syncthreads();
        if (tt < 40) {
            int ww = tt / 10, c = tt % 10;
            float acc = b_out[c];
#pragma unroll
            for (int i = 0; i < 40; ++i) acc += Hl[ww][i] * W_out[i * 10 + c];
            out[(size_t)(blockIdx.x * 4 + ww) * 10 + c] = acc;
        }
    }
}

extern "C" void kernel_launch(void* const* d_in, const int* in_sizes, int n_in,
                              void* d_out, int out_size, void* d_ws, size_t ws_size,
                              hipStream_t stream) {
    const float* feat   = (const float*)d_in[0];
    const int*   ei     = (const int*)d_in[1];
    const float* W_in   = (const float*)d_in[2];
    const float* b_in   = (const float*)d_in[3];
    const float* Wq     = (const float*)d_in[4];
    const float* bq     = (const float*)d_in[5];
    const float* Wk     = (const float*)d_in[6];
    const float* bk     = (const float*)d_in[7];
    const float* Wv     = (const float*)d_in[8];
    const float* bv     = (const float*)d_in[9];
    const float* W_out  = (const float*)d_in[10];
    const float* b_out  = (const float*)d_in[11];
    const float* hopwise= (const float*)d_in[12];
    const float* temp   = (const float*)d_in[13];
    float* out = (float*)d_out;

    char* ws = (char*)d_ws;
    size_t off = 0;
    auto alloc = [&](size_t bytes) -> void* {
        void* p = ws + off;
        off += (bytes + 255) & ~(size_t)255;
        return p;
    };
    int*      deg    = (int*)alloc((size_t)kN * 4);
    int*      cursor = (int*)alloc((size_t)kN * 4);
    int*      ptr    = (int*)alloc((size_t)(kN + 1) * 4);
    int*      csrc   = (int*)alloc((size_t)kET * 4);
    float*    cwgt   = (float*)alloc((size_t)kET * 4);
    float*    Q      = (float*)alloc((size_t)kN * kHID * 4);
    float*    Kt0    = (float*)alloc((size_t)kN * kHID * 4);
    float*    Kt1    = (float*)alloc((size_t)kN * kHID * 4);
    float*    hidden = (float*)alloc((size_t)kN * kH * kC * 4);
    float*    gammas = (float*)alloc(64);
    uint16_t* M0     = (uint16_t*)alloc((size_t)kN * 640 * 2);
    uint16_t* M1     = (uint16_t*)alloc((size_t)kN * 640 * 2);
    (void)ws_size; (void)in_sizes; (void)n_in; (void)out_size;

    // deg & cursor are adjacent in ws: one memset covers both
    size_t deg_span = (size_t)((char*)cursor - (char*)deg) + (size_t)kN * 4;
    hipMemsetAsync(deg, 0, deg_span, stream);

    deg_kernel<<<(kET + 255) / 256, 256, 0, stream>>>(ei, deg);
    scan_kernel<<<1, 1024, 0, stream>>>(deg, ptr, hopwise, temp, gammas);
    scatter_kernel<<<(kET + 255) / 256, 256, 0, stream>>>(ei, deg, ptr, cursor, csrc, cwgt);
    proj_kernel<<<kN / kBN, 256, 0, stream>>>(feat, W_in, b_in, Wq, bq, Wk, bk, Wv, bv,
                                              hopwise, Q, Kt0, hidden, M0);
    hop2_kernel<false><<<kN / 4, 256, 0, stream>>>(ptr, csrc, cwgt, M0, M1, Kt0, Kt1, Q, hidden,
                                                   gammas + 0, W_out, b_out, out);
    hop2_kernel<false><<<kN / 4, 256, 0, stream>>>(ptr, csrc, cwgt, M1, M0, Kt1, Kt0, Q, hidden,
                                                   gammas + 4, W_out, b_out, out);
    hop2_kernel<true><<<kN / 4, 256, 0, stream>>>(ptr, csrc, cwgt, M0, M1, Kt0, Kt1, Q, hidden,
                                                  gammas + 8, W_out, b_out, out);
}